// Round 1
// baseline (429.700 us; speedup 1.0000x reference)
//
#include <hip/hip_runtime.h>

#define BB 16
#define HH 256
#define WW 256
#define CC 16
#define HID 128
#define TS 16
#define TP (TS + 2)

// ---------------------------------------------------------------------------
// prep: transpose w1 (C x HID) -> w1t (HID x C) so the hot loop reads a
// contiguous 16-float row per hidden unit (one s_load_dwordx16).
// ---------------------------------------------------------------------------
__global__ void prep_w1t(const float* __restrict__ w1, float* __restrict__ w1t) {
    int i = blockIdx.x * blockDim.x + threadIdx.x;
    if (i < CC * HID) {
        int c = i / HID;
        int o = i % HID;
        w1t[o * CC + c] = w1[i];
    }
}

// ---------------------------------------------------------------------------
// pass1: perceive + MLP + stochastic update. Writes x_new to out,
// x_new alpha and pre_life flags to workspace planes.
// ---------------------------------------------------------------------------
__global__ __launch_bounds__(256)
void pass1(const float* __restrict__ x, const float* __restrict__ w0,
           const float* __restrict__ w1t, const float* __restrict__ rand_mask,
           float* __restrict__ xn_out, float* __restrict__ alpha_out,
           float* __restrict__ pre_out)
{
    // tile layout [c][y][x]: lane-consecutive x -> stride-1 LDS (few conflicts)
    __shared__ float tile[CC][TP][TP];

    const int tx = threadIdx.x, ty = threadIdx.y;
    const int bx = blockIdx.x * TS, by = blockIdx.y * TS, b = blockIdx.z;
    const int tid = ty * TS + tx;
    const float* xb = x + (size_t)b * HH * WW * CC;

    // cooperative halo load; global reads coalesced (c fastest), OOB -> 0
    for (int idx = tid; idx < TP * TP * CC; idx += 256) {
        int c = idx & (CC - 1);
        int p = idx >> 4;
        int ly = p / TP, lx = p % TP;
        int gy = by + ly - 1, gx = bx + lx - 1;
        float v = 0.f;
        if (gy >= 0 && gy < HH && gx >= 0 && gx < WW)
            v = xb[((size_t)gy * WW + gx) * CC + c];
        tile[c][ly][lx] = v;
    }
    __syncthreads();

    const int ly = ty + 1, lx = tx + 1;

    // perceive: y[3c]=ident, y[3c+1]=sobel_x, y[3c+2]=sobel_y
    float y[3 * CC];
    #pragma unroll
    for (int c = 0; c < CC; ++c) {
        float a00 = tile[c][ly - 1][lx - 1], a01 = tile[c][ly - 1][lx], a02 = tile[c][ly - 1][lx + 1];
        float a10 = tile[c][ly    ][lx - 1], a11 = tile[c][ly    ][lx], a12 = tile[c][ly    ][lx + 1];
        float a20 = tile[c][ly + 1][lx - 1], a21 = tile[c][ly + 1][lx], a22 = tile[c][ly + 1][lx + 1];
        y[3 * c + 0] = a11;
        y[3 * c + 1] = ((a02 + 2.f * a12 + a22) - (a00 + 2.f * a10 + a20)) * 0.125f;
        y[3 * c + 2] = ((a20 + 2.f * a21 + a22) - (a00 + 2.f * a01 + a02)) * 0.125f;
    }

    // pre_life: 3x3 max of alpha (channel 3) > 0.1 (0-pad == -inf pad here)
    float mx;
    {
        float m0 = fmaxf(fmaxf(tile[3][ly - 1][lx - 1], tile[3][ly - 1][lx]), tile[3][ly - 1][lx + 1]);
        float m1 = fmaxf(fmaxf(tile[3][ly    ][lx - 1], tile[3][ly    ][lx]), tile[3][ly    ][lx + 1]);
        float m2 = fmaxf(fmaxf(tile[3][ly + 1][lx - 1], tile[3][ly + 1][lx]), tile[3][ly + 1][lx + 1]);
        mx = fmaxf(fmaxf(m0, m1), m2);
    }
    const float pre = (mx > 0.1f) ? 1.f : 0.f;

    // MLP: dx1 = relu(w0 @ y); dx = w1 @ dx1.
    // w0/w1t indices are wave-uniform -> compiler emits scalar loads (SMEM pipe).
    float dx[CC];
    #pragma unroll
    for (int c = 0; c < CC; ++c) dx[c] = 0.f;

    for (int o = 0; o < HID; ++o) {
        const float* w0r = w0 + o * 48;
        float h0 = 0.f, h1 = 0.f, h2 = 0.f, h3 = 0.f;
        #pragma unroll
        for (int k = 0; k < 48; k += 4) {
            h0 = fmaf(w0r[k + 0], y[k + 0], h0);
            h1 = fmaf(w0r[k + 1], y[k + 1], h1);
            h2 = fmaf(w0r[k + 2], y[k + 2], h2);
            h3 = fmaf(w0r[k + 3], y[k + 3], h3);
        }
        float h = fmaxf((h0 + h1) + (h2 + h3), 0.f);
        const float* w1r = w1t + o * CC;
        #pragma unroll
        for (int c = 0; c < CC; ++c) dx[c] = fmaf(w1r[c], h, dx[c]);
    }

    const size_t pix = (size_t)b * HH * WW + (size_t)(by + ty) * WW + (bx + tx);
    const float upd = (rand_mask[pix] <= 0.5f) ? 1.f : 0.f;

    float xn[CC];
    #pragma unroll
    for (int c = 0; c < CC; ++c) xn[c] = y[3 * c] + dx[c] * upd; // STEP_SIZE=1

    float4* outv = (float4*)(xn_out + pix * CC);
    #pragma unroll
    for (int i = 0; i < 4; ++i)
        outv[i] = make_float4(xn[4 * i], xn[4 * i + 1], xn[4 * i + 2], xn[4 * i + 3]);

    alpha_out[pix] = xn[3];
    pre_out[pix] = pre;
}

// ---------------------------------------------------------------------------
// pass2: post_life from x_new alpha, AND with pre_life, masked rewrite of out.
// ---------------------------------------------------------------------------
__global__ __launch_bounds__(256)
void pass2(const float* __restrict__ alpha, const float* __restrict__ pre,
           float* __restrict__ out)
{
    __shared__ float at[TP][TP];
    const int tx = threadIdx.x, ty = threadIdx.y;
    const int bx = blockIdx.x * TS, by = blockIdx.y * TS, b = blockIdx.z;
    const int tid = ty * TS + tx;
    const float* ab = alpha + (size_t)b * HH * WW;

    for (int idx = tid; idx < TP * TP; idx += 256) {
        int ly = idx / TP, lx = idx % TP;
        int gy = by + ly - 1, gx = bx + lx - 1;
        float v = 0.f;
        if (gy >= 0 && gy < HH && gx >= 0 && gx < WW) v = ab[gy * WW + gx];
        at[ly][lx] = v;
    }
    __syncthreads();

    const int ly = ty + 1, lx = tx + 1;
    float m0 = fmaxf(fmaxf(at[ly - 1][lx - 1], at[ly - 1][lx]), at[ly - 1][lx + 1]);
    float m1 = fmaxf(fmaxf(at[ly    ][lx - 1], at[ly    ][lx]), at[ly    ][lx + 1]);
    float m2 = fmaxf(fmaxf(at[ly + 1][lx - 1], at[ly + 1][lx]), at[ly + 1][lx + 1]);
    float m = fmaxf(fmaxf(m0, m1), m2);

    const size_t pix = (size_t)b * HH * WW + (size_t)(by + ty) * WW + (bx + tx);
    const float life = (m > 0.1f && pre[pix] > 0.5f) ? 1.f : 0.f;

    float4* o4 = (float4*)(out + pix * CC);
    #pragma unroll
    for (int i = 0; i < 4; ++i) {
        float4 v = o4[i];
        v.x *= life; v.y *= life; v.z *= life; v.w *= life;
        o4[i] = v;
    }
}

extern "C" void kernel_launch(void* const* d_in, const int* in_sizes, int n_in,
                              void* d_out, int out_size, void* d_ws, size_t ws_size,
                              hipStream_t stream) {
    const float* x  = (const float*)d_in[0];
    const float* w0 = (const float*)d_in[1];
    const float* w1 = (const float*)d_in[2];
    const float* rm = (const float*)d_in[3];
    float* out = (float*)d_out;

    float* ws    = (float*)d_ws;
    float* alpha = ws;                                  // B*H*W floats
    float* pre   = ws + (size_t)BB * HH * WW;           // B*H*W floats
    float* w1t   = ws + 2 * (size_t)BB * HH * WW;       // HID*C floats

    prep_w1t<<<(CC * HID + 255) / 256, 256, 0, stream>>>(w1, w1t);

    dim3 grid(WW / TS, HH / TS, BB);
    dim3 blk(TS, TS);
    pass1<<<grid, blk, 0, stream>>>(x, w0, w1t, rm, out, alpha, pre);
    pass2<<<grid, blk, 0, stream>>>(alpha, pre, out);
}

// Round 2
// 237.861 us; speedup vs baseline: 1.8065x; 1.8065x over previous
//
#include <hip/hip_runtime.h>

#define BB 16
#define HH 256
#define WW 256
#define CC 16
#define HID 128
#define TS 16
#define NPIX ((size_t)BB * HH * WW)

typedef __attribute__((ext_vector_type(8))) short short8;
typedef __attribute__((ext_vector_type(4))) float floatx4;

__device__ inline unsigned int f2bf(float f) {
    unsigned int u = __float_as_uint(f);
    return (u + 0x7FFFu + ((u >> 16) & 1u)) >> 16;   // RNE
}
__device__ inline unsigned int pack2(float lo, float hi) {
    return f2bf(lo) | (f2bf(hi) << 16);
}
__device__ inline void unpack8(const unsigned short* p, float* f) {
    uint4 d = *(const uint4*)p;   // one ds_read_b128, 8 bf16
    f[0] = __uint_as_float(d.x << 16); f[1] = __uint_as_float(d.x & 0xFFFF0000u);
    f[2] = __uint_as_float(d.y << 16); f[3] = __uint_as_float(d.y & 0xFFFF0000u);
    f[4] = __uint_as_float(d.z << 16); f[5] = __uint_as_float(d.z & 0xFFFF0000u);
    f[6] = __uint_as_float(d.w << 16); f[7] = __uint_as_float(d.w & 0xFFFF0000u);
}

// ---------------------------------------------------------------------------
// prep: cast weights to bf16. w0b[o][k] 128x64 (k 48..63 zero-padded),
// w1b[o][c] 16x128 (natural layout). Both give contiguous 16B A/B-frag loads.
// ---------------------------------------------------------------------------
__global__ void prep(const float* __restrict__ w0, const float* __restrict__ w1,
                     unsigned short* __restrict__ w0b, unsigned short* __restrict__ w1b) {
    int i = blockIdx.x * blockDim.x + threadIdx.x;
    if (i < HID * 64) {
        int o = i >> 6, k = i & 63;
        w0b[i] = (k < 48) ? (unsigned short)f2bf(w0[o * 48 + k]) : (unsigned short)0;
    }
    if (i < CC * HID) w1b[i] = (unsigned short)f2bf(w1[i]);
}

// ---------------------------------------------------------------------------
// pass1: perceive (bf16 LDS tile) + MFMA MLP + stochastic update.
// GEMM1: H^T[n][p] = sum_k W0[n][k] Y[p][k]   (A=w0b rows, B=Y rows)
// GEMM2: DX^T[o][p] = sum_c W1[o][c] H[p][c]  (A=w1b rows, B=H rows)
// C/D layout: col=lane&15, row=quad*4+reg  (m89/m91-verified)
// ---------------------------------------------------------------------------
__global__ __launch_bounds__(256)
void pass1(const float* __restrict__ x, const unsigned short* __restrict__ w0b,
           const unsigned short* __restrict__ w1b, const float* __restrict__ rand_mask,
           float* __restrict__ xn_out, float* __restrict__ alpha_out,
           float* __restrict__ pre_out)
{
    __shared__ unsigned short Ylds[256 * 72];          // 36864 B, row stride 72 bf16 (16B-aligned, bank-spread)
    __shared__ __align__(16) char uregion[4 * 16 * 136 * 2];  // 17408 B: xt (phase1) / Hb (phase2)
    unsigned short* xt = (unsigned short*)uregion;     // [18*18][24] bf16 tile (15552 B used)
    unsigned short* Hb = (unsigned short*)uregion;     // 4 waves x [16][136] bf16

    const int tx = threadIdx.x, ty = threadIdx.y;
    const int bx = blockIdx.x * TS, by = blockIdx.y * TS, b = blockIdx.z;
    const int tid = ty * TS + tx;
    const float* xb = x + (size_t)b * HH * WW * CC;

    // ---- phase 1a: halo tile -> bf16 LDS, pixel stride 24 (48B, 16B mult) ----
    for (int idx = tid; idx < 18 * 18 * 4; idx += 256) {
        int cq = idx & 3, p = idx >> 2;
        int lyy = p / 18, lxx = p % 18;
        int gy = by + lyy - 1, gx = bx + lxx - 1;
        float4 v = make_float4(0.f, 0.f, 0.f, 0.f);
        if (gy >= 0 && gy < HH && gx >= 0 && gx < WW)
            v = *(const float4*)(xb + (size_t)(gy * WW + gx) * CC + cq * 4);
        *(uint2*)(xt + p * 24 + cq * 4) = make_uint2(pack2(v.x, v.y), pack2(v.z, v.w));
    }
    __syncthreads();

    // ---- phase 1b: perceive + pre_life, build Y row ----
    float yv[48];
    float amax = -1.f;
    #pragma unroll
    for (int cq = 0; cq < 2; ++cq) {
        float sx[8], sy[8], ct[8];
        #pragma unroll
        for (int e = 0; e < 8; ++e) { sx[e] = 0.f; sy[e] = 0.f; }
        #pragma unroll
        for (int dy = 0; dy < 3; ++dy) {
            float fl[8], fm[8], fr[8];
            const unsigned short* rowp = xt + ((ty + dy) * 18 + tx) * 24 + cq * 8;
            unpack8(rowp, fl);
            unpack8(rowp + 24, fm);
            unpack8(rowp + 48, fr);
            #pragma unroll
            for (int e = 0; e < 8; ++e) {
                float d = fr[e] - fl[e];
                sx[e] += (dy == 1) ? (d + d) : d;
                float rs = fl[e] + 2.f * fm[e] + fr[e];
                if (dy == 0) sy[e] -= rs;
                if (dy == 2) sy[e] += rs;
                if (dy == 1) ct[e] = fm[e];
            }
            if (cq == 0) amax = fmaxf(amax, fmaxf(fmaxf(fl[3], fm[3]), fr[3]));
        }
        #pragma unroll
        for (int e = 0; e < 8; ++e) {
            int c = cq * 8 + e;
            yv[3 * c + 0] = ct[e];
            yv[3 * c + 1] = sx[e] * 0.125f;
            yv[3 * c + 2] = sy[e] * 0.125f;
        }
    }

    {
        const size_t pix0 = (size_t)b * HH * WW + (size_t)(by + ty) * WW + (bx + tx);
        pre_out[pix0] = (amax > 0.1f) ? 1.f : 0.f;
    }

    {   // Y row: 48 bf16 + 16 zeros (K padded to 64; w0b pad also zero)
        unsigned int yw[24];
        #pragma unroll
        for (int j = 0; j < 24; ++j) yw[j] = pack2(yv[2 * j], yv[2 * j + 1]);
        unsigned short* yrow = Ylds + tid * 72;
        #pragma unroll
        for (int j = 0; j < 6; ++j)
            *(uint4*)(yrow + j * 8) = make_uint4(yw[4 * j], yw[4 * j + 1], yw[4 * j + 2], yw[4 * j + 3]);
        *(uint4*)(yrow + 48) = make_uint4(0, 0, 0, 0);
        *(uint4*)(yrow + 56) = make_uint4(0, 0, 0, 0);
    }
    __syncthreads();   // xt dead beyond here; uregion becomes Hb

    // ---- phase 2: MFMA MLP, wave-private (wave w owns pixels [64w, 64w+64)) ----
    const int w = tid >> 6, lane = tid & 63;
    const int quad = lane >> 4, lr = lane & 15;

    short8 A0[8][2];   // w0b A-frags: A[m=lr][k=quad*8+j], m-tile x k-step
    #pragma unroll
    for (int mt = 0; mt < 8; ++mt)
        #pragma unroll
        for (int ks = 0; ks < 2; ++ks)
            A0[mt][ks] = *(const short8*)(w0b + (mt * 16 + lr) * 64 + ks * 32 + quad * 8);
    short8 A1[4];      // w1b A-frags
    #pragma unroll
    for (int ks = 0; ks < 4; ++ks)
        A1[ks] = *(const short8*)(w1b + lr * 128 + ks * 32 + quad * 8);

    unsigned short* Hw = Hb + w * 16 * 136;   // wave-private H buffer [16 px][136]

    for (int nt = 0; nt < 4; ++nt) {
        const int pb = w * 64 + nt * 16;
        // B-frags for GEMM1: Y rows (contiguous k)
        short8 B0 = *(const short8*)(Ylds + (pb + lr) * 72 + quad * 8);
        short8 B1 = *(const short8*)(Ylds + (pb + lr) * 72 + 32 + quad * 8);

        // WAR guard: previous iteration's H reads must drain before overwrite
        asm volatile("s_waitcnt lgkmcnt(0)" ::: "memory");

        #pragma unroll
        for (int mt = 0; mt < 8; ++mt) {
            floatx4 acc = {0.f, 0.f, 0.f, 0.f};
            acc = __builtin_amdgcn_mfma_f32_16x16x32_bf16(A0[mt][0], B0, acc, 0, 0, 0);
            acc = __builtin_amdgcn_mfma_f32_16x16x32_bf16(A0[mt][1], B1, acc, 0, 0, 0);
            // lane holds H[pixel=lr][hidden=mt*16+quad*4+r], r=0..3 -> relu+pack -> b64
            unsigned int lo = pack2(fmaxf(acc[0], 0.f), fmaxf(acc[1], 0.f));
            unsigned int hi = pack2(fmaxf(acc[2], 0.f), fmaxf(acc[3], 0.f));
            *(uint2*)(Hw + lr * 136 + mt * 16 + quad * 4) = make_uint2(lo, hi);
        }
        // RAW guard: H writes (incl. other lanes of this wave) before B2 reads
        asm volatile("s_waitcnt lgkmcnt(0)" ::: "memory");

        floatx4 dacc = {0.f, 0.f, 0.f, 0.f};
        #pragma unroll
        for (int ks = 0; ks < 4; ++ks) {
            short8 Bh = *(const short8*)(Hw + lr * 136 + ks * 32 + quad * 8);
            dacc = __builtin_amdgcn_mfma_f32_16x16x32_bf16(A1[ks], Bh, dacc, 0, 0, 0);
        }

        // epilogue: lane holds dx[pixel=pb+lr][o=quad*4+r]
        const int gy = by + w * 4 + nt, gx = bx + lr;
        const size_t pix = (size_t)b * HH * WW + (size_t)gy * WW + gx;
        const float upd = (rand_mask[pix] <= 0.5f) ? 1.f : 0.f;
        const float4 xc = *(const float4*)(x + pix * CC + quad * 4);
        float4 xn;
        xn.x = xc.x + dacc[0] * upd;
        xn.y = xc.y + dacc[1] * upd;
        xn.z = xc.z + dacc[2] * upd;
        xn.w = xc.w + dacc[3] * upd;
        *(float4*)(xn_out + pix * CC + quad * 4) = xn;
        if (quad == 0) alpha_out[pix] = xn.w;   // channel 3
    }
}

// ---------------------------------------------------------------------------
// pass2: post_life from x_new alpha, AND with pre_life, masked rewrite of out.
// ---------------------------------------------------------------------------
#define TP (TS + 2)
__global__ __launch_bounds__(256)
void pass2(const float* __restrict__ alpha, const float* __restrict__ pre,
           float* __restrict__ out)
{
    __shared__ float at[TP][TP];
    const int tx = threadIdx.x, ty = threadIdx.y;
    const int bx = blockIdx.x * TS, by = blockIdx.y * TS, b = blockIdx.z;
    const int tid = ty * TS + tx;
    const float* ab = alpha + (size_t)b * HH * WW;

    for (int idx = tid; idx < TP * TP; idx += 256) {
        int ly = idx / TP, lx = idx % TP;
        int gy = by + ly - 1, gx = bx + lx - 1;
        float v = 0.f;
        if (gy >= 0 && gy < HH && gx >= 0 && gx < WW) v = ab[gy * WW + gx];
        at[ly][lx] = v;
    }
    __syncthreads();

    const int ly = ty + 1, lx = tx + 1;
    float m0 = fmaxf(fmaxf(at[ly - 1][lx - 1], at[ly - 1][lx]), at[ly - 1][lx + 1]);
    float m1 = fmaxf(fmaxf(at[ly    ][lx - 1], at[ly    ][lx]), at[ly    ][lx + 1]);
    float m2 = fmaxf(fmaxf(at[ly + 1][lx - 1], at[ly + 1][lx]), at[ly + 1][lx + 1]);
    float m = fmaxf(fmaxf(m0, m1), m2);

    const size_t pix = (size_t)b * HH * WW + (size_t)(by + ty) * WW + (bx + tx);
    const float life = (m > 0.1f && pre[pix] > 0.5f) ? 1.f : 0.f;

    float4* o4 = (float4*)(out + pix * CC);
    #pragma unroll
    for (int i = 0; i < 4; ++i) {
        float4 v = o4[i];
        v.x *= life; v.y *= life; v.z *= life; v.w *= life;
        o4[i] = v;
    }
}

extern "C" void kernel_launch(void* const* d_in, const int* in_sizes, int n_in,
                              void* d_out, int out_size, void* d_ws, size_t ws_size,
                              hipStream_t stream) {
    const float* x  = (const float*)d_in[0];
    const float* w0 = (const float*)d_in[1];
    const float* w1 = (const float*)d_in[2];
    const float* rm = (const float*)d_in[3];
    float* out = (float*)d_out;

    float* ws    = (float*)d_ws;
    float* alpha = ws;                         // B*H*W floats
    float* pre   = ws + NPIX;                  // B*H*W floats
    unsigned short* w0b = (unsigned short*)(ws + 2 * NPIX);  // 128*64 bf16
    unsigned short* w1b = w0b + HID * 64;                    // 16*128 bf16

    prep<<<32, 256, 0, stream>>>(w0, w1, w0b, w1b);

    dim3 grid(WW / TS, HH / TS, BB);
    dim3 blk(TS, TS);
    pass1<<<grid, blk, 0, stream>>>(x, w0b, w1b, rm, out, alpha, pre);
    pass2<<<grid, blk, 0, stream>>>(alpha, pre, out);
}

// Round 3
// 197.719 us; speedup vs baseline: 2.1733x; 1.2030x over previous
//
#include <hip/hip_runtime.h>

#define BB 16
#define HH 256
#define WW 256
#define CC 16
#define HID 128
#define TS 16
#define NPIX ((size_t)BB * HH * WW)
#define YSTR 56   // Y row stride in bf16; k=48..55 zero pad, 56..63 reads spill (x0 weight)

typedef __attribute__((ext_vector_type(8))) short short8;
typedef __attribute__((ext_vector_type(4))) float floatx4;

__device__ inline unsigned int f2bf(float f) {
    unsigned int u = __float_as_uint(f);
    return (u + 0x7FFFu + ((u >> 16) & 1u)) >> 16;   // RNE
}
__device__ inline unsigned int pack2(float lo, float hi) {
    return f2bf(lo) | (f2bf(hi) << 16);
}
__device__ inline void unpack8(const unsigned short* p, float* f) {
    uint4 d = *(const uint4*)p;   // one ds_read_b128, 8 bf16
    f[0] = __uint_as_float(d.x << 16); f[1] = __uint_as_float(d.x & 0xFFFF0000u);
    f[2] = __uint_as_float(d.y << 16); f[3] = __uint_as_float(d.y & 0xFFFF0000u);
    f[4] = __uint_as_float(d.z << 16); f[5] = __uint_as_float(d.z & 0xFFFF0000u);
    f[6] = __uint_as_float(d.w << 16); f[7] = __uint_as_float(d.w & 0xFFFF0000u);
}

// ---------------------------------------------------------------------------
// prep: cast weights to bf16. w0b[o][k] 128x64 (k 48..63 zero-padded),
// w1b[o][c] 16x128.
// ---------------------------------------------------------------------------
__global__ void prep(const float* __restrict__ w0, const float* __restrict__ w1,
                     unsigned short* __restrict__ w0b, unsigned short* __restrict__ w1b) {
    int i = blockIdx.x * blockDim.x + threadIdx.x;
    if (i < HID * 64) {
        int o = i >> 6, k = i & 63;
        w0b[i] = (k < 48) ? (unsigned short)f2bf(w0[o * 48 + k]) : (unsigned short)0;
    }
    if (i < CC * HID) w1b[i] = (unsigned short)f2bf(w1[i]);
}

// ---------------------------------------------------------------------------
// pass1: perceive (bf16 LDS tile) + MFMA MLP + stochastic update.
// GEMM1: H^T[n][p] = sum_k W0[n][k] Y[p][k]   (A=w0b rows, B=Y rows)
// GEMM2: DX^T[o][p] = sum_c W1[o][c] H[p][c]  (A=w1b rows, B=H rows)
// C/D layout: col=lane&15, row=quad*4+reg  (m89/m91-verified)
// LDS: 28672 (Y) + 17408 (xt/Hb union) = 46080 B -> 3 blocks/CU
// ---------------------------------------------------------------------------
__global__ __launch_bounds__(256)
void pass1(const float* __restrict__ x, const unsigned short* __restrict__ w0b,
           const unsigned short* __restrict__ w1b, const float* __restrict__ rand_mask,
           float* __restrict__ xn_out, float* __restrict__ alpha_out,
           float* __restrict__ pre_out)
{
    __shared__ unsigned short Ylds[256 * YSTR];               // 28672 B
    __shared__ __align__(16) char uregion[4 * 16 * 136 * 2];  // 17408 B: xt (phase1) / Hb (phase2)
    unsigned short* xt = (unsigned short*)uregion;     // [18*18][24] bf16 tile (15552 B used)
    unsigned short* Hb = (unsigned short*)uregion;     // 4 waves x [16][136] bf16

    const int tx = threadIdx.x, ty = threadIdx.y;
    const int bx = blockIdx.x * TS, by = blockIdx.y * TS, b = blockIdx.z;
    const int tid = ty * TS + tx;
    const float* xb = x + (size_t)b * HH * WW * CC;

    // ---- phase 1a: halo tile -> bf16 LDS, pixel stride 24 (48B, 16B mult) ----
    for (int idx = tid; idx < 18 * 18 * 4; idx += 256) {
        int cq = idx & 3, p = idx >> 2;
        int lyy = p / 18, lxx = p % 18;
        int gy = by + lyy - 1, gx = bx + lxx - 1;
        float4 v = make_float4(0.f, 0.f, 0.f, 0.f);
        if (gy >= 0 && gy < HH && gx >= 0 && gx < WW)
            v = *(const float4*)(xb + (size_t)(gy * WW + gx) * CC + cq * 4);
        *(uint2*)(xt + p * 24 + cq * 4) = make_uint2(pack2(v.x, v.y), pack2(v.z, v.w));
    }
    __syncthreads();

    // ---- phase 1b: perceive + pre_life, build Y row ----
    float yv[48];
    float amax = -1.f;
    #pragma unroll
    for (int cq = 0; cq < 2; ++cq) {
        float sx[8], sy[8], ct[8];
        #pragma unroll
        for (int e = 0; e < 8; ++e) { sx[e] = 0.f; sy[e] = 0.f; }
        #pragma unroll
        for (int dy = 0; dy < 3; ++dy) {
            float fl[8], fm[8], fr[8];
            const unsigned short* rowp = xt + ((ty + dy) * 18 + tx) * 24 + cq * 8;
            unpack8(rowp, fl);
            unpack8(rowp + 24, fm);
            unpack8(rowp + 48, fr);
            #pragma unroll
            for (int e = 0; e < 8; ++e) {
                float d = fr[e] - fl[e];
                sx[e] += (dy == 1) ? (d + d) : d;
                float rs = fl[e] + 2.f * fm[e] + fr[e];
                if (dy == 0) sy[e] -= rs;
                if (dy == 2) sy[e] += rs;
                if (dy == 1) ct[e] = fm[e];
            }
            if (cq == 0) amax = fmaxf(amax, fmaxf(fmaxf(fl[3], fm[3]), fr[3]));
        }
        #pragma unroll
        for (int e = 0; e < 8; ++e) {
            int c = cq * 8 + e;
            yv[3 * c + 0] = ct[e];
            yv[3 * c + 1] = sx[e] * 0.125f;
            yv[3 * c + 2] = sy[e] * 0.125f;
        }
    }

    {
        const size_t pix0 = (size_t)b * HH * WW + (size_t)(by + ty) * WW + (bx + tx);
        pre_out[pix0] = (amax > 0.1f) ? 1.f : 0.f;
    }

    {   // Y row: 48 bf16 data + 8 bf16 zero pad (k=48..55; k=56..63 read as
        // neighbor-row garbage, multiplied by zero w0b pad -> contributes 0)
        unsigned int yw[24];
        #pragma unroll
        for (int j = 0; j < 24; ++j) yw[j] = pack2(yv[2 * j], yv[2 * j + 1]);
        unsigned short* yrow = Ylds + tid * YSTR;
        #pragma unroll
        for (int j = 0; j < 6; ++j)
            *(uint4*)(yrow + j * 8) = make_uint4(yw[4 * j], yw[4 * j + 1], yw[4 * j + 2], yw[4 * j + 3]);
        *(uint4*)(yrow + 48) = make_uint4(0, 0, 0, 0);
    }
    __syncthreads();   // xt dead beyond here; uregion becomes Hb

    // ---- phase 2: MFMA MLP, wave-private (wave w owns pixels [64w, 64w+64)) ----
    const int w = tid >> 6, lane = tid & 63;
    const int quad = lane >> 4, lr = lane & 15;

    short8 A0[8][2];   // w0b A-frags: A[m=lr][k=quad*8+j]
    #pragma unroll
    for (int mt = 0; mt < 8; ++mt)
        #pragma unroll
        for (int ks = 0; ks < 2; ++ks)
            A0[mt][ks] = *(const short8*)(w0b + (mt * 16 + lr) * 64 + ks * 32 + quad * 8);
    short8 A1[4];      // w1b A-frags
    #pragma unroll
    for (int ks = 0; ks < 4; ++ks)
        A1[ks] = *(const short8*)(w1b + lr * 128 + ks * 32 + quad * 8);

    unsigned short* Hw = Hb + w * 16 * 136;   // wave-private H buffer [16 px][136]

    for (int nt = 0; nt < 4; ++nt) {
        const int pb = w * 64 + nt * 16;
        short8 B0 = *(const short8*)(Ylds + (pb + lr) * YSTR + quad * 8);
        short8 B1 = *(const short8*)(Ylds + (pb + lr) * YSTR + 32 + quad * 8);

        // WAR guard: previous iteration's H reads must drain before overwrite
        asm volatile("s_waitcnt lgkmcnt(0)" ::: "memory");

        #pragma unroll
        for (int mt = 0; mt < 8; ++mt) {
            floatx4 acc = {0.f, 0.f, 0.f, 0.f};
            acc = __builtin_amdgcn_mfma_f32_16x16x32_bf16(A0[mt][0], B0, acc, 0, 0, 0);
            acc = __builtin_amdgcn_mfma_f32_16x16x32_bf16(A0[mt][1], B1, acc, 0, 0, 0);
            unsigned int lo = pack2(fmaxf(acc[0], 0.f), fmaxf(acc[1], 0.f));
            unsigned int hi = pack2(fmaxf(acc[2], 0.f), fmaxf(acc[3], 0.f));
            *(uint2*)(Hw + lr * 136 + mt * 16 + quad * 4) = make_uint2(lo, hi);
        }
        // RAW guard: H writes (incl. other lanes of this wave) before reads
        asm volatile("s_waitcnt lgkmcnt(0)" ::: "memory");

        floatx4 dacc = {0.f, 0.f, 0.f, 0.f};
        #pragma unroll
        for (int ks = 0; ks < 4; ++ks) {
            short8 Bh = *(const short8*)(Hw + lr * 136 + ks * 32 + quad * 8);
            dacc = __builtin_amdgcn_mfma_f32_16x16x32_bf16(A1[ks], Bh, dacc, 0, 0, 0);
        }

        // epilogue: lane holds dx[pixel=pb+lr][o=quad*4+r]
        const int gy = by + w * 4 + nt, gx = bx + lr;
        const size_t pix = (size_t)b * HH * WW + (size_t)gy * WW + gx;
        const float upd = (rand_mask[pix] <= 0.5f) ? 1.f : 0.f;
        const float4 xc = *(const float4*)(x + pix * CC + quad * 4);
        float4 xn;
        xn.x = xc.x + dacc[0] * upd;
        xn.y = xc.y + dacc[1] * upd;
        xn.z = xc.z + dacc[2] * upd;
        xn.w = xc.w + dacc[3] * upd;
        *(float4*)(xn_out + pix * CC + quad * 4) = xn;
        if (quad == 0) alpha_out[pix] = xn.w;   // channel 3
    }
}

// ---------------------------------------------------------------------------
// pass2: out already holds xn. Only dead pixels (life==0) need zeroing —
// reads 8.4 MB of alpha/pre planes, writes only where life flips to 0.
// ---------------------------------------------------------------------------
#define TP (TS + 2)
__global__ __launch_bounds__(256)
void pass2(const float* __restrict__ alpha, const float* __restrict__ pre,
           float* __restrict__ out)
{
    __shared__ float at[TP][TP];
    const int tx = threadIdx.x, ty = threadIdx.y;
    const int bx = blockIdx.x * TS, by = blockIdx.y * TS, b = blockIdx.z;
    const int tid = ty * TS + tx;
    const float* ab = alpha + (size_t)b * HH * WW;

    for (int idx = tid; idx < TP * TP; idx += 256) {
        int ly = idx / TP, lx = idx % TP;
        int gy = by + ly - 1, gx = bx + lx - 1;
        float v = 0.f;
        if (gy >= 0 && gy < HH && gx >= 0 && gx < WW) v = ab[gy * WW + gx];
        at[ly][lx] = v;
    }
    __syncthreads();

    const int ly = ty + 1, lx = tx + 1;
    float m0 = fmaxf(fmaxf(at[ly - 1][lx - 1], at[ly - 1][lx]), at[ly - 1][lx + 1]);
    float m1 = fmaxf(fmaxf(at[ly    ][lx - 1], at[ly    ][lx]), at[ly    ][lx + 1]);
    float m2 = fmaxf(fmaxf(at[ly + 1][lx - 1], at[ly + 1][lx]), at[ly + 1][lx + 1]);
    float m = fmaxf(fmaxf(m0, m1), m2);

    const size_t pix = (size_t)b * HH * WW + (size_t)(by + ty) * WW + (bx + tx);
    const bool dead = !(m > 0.1f && pre[pix] > 0.5f);

    if (dead) {
        float4 z = make_float4(0.f, 0.f, 0.f, 0.f);
        float4* o4 = (float4*)(out + pix * CC);
        #pragma unroll
        for (int i = 0; i < 4; ++i) o4[i] = z;
    }
}

extern "C" void kernel_launch(void* const* d_in, const int* in_sizes, int n_in,
                              void* d_out, int out_size, void* d_ws, size_t ws_size,
                              hipStream_t stream) {
    const float* x  = (const float*)d_in[0];
    const float* w0 = (const float*)d_in[1];
    const float* w1 = (const float*)d_in[2];
    const float* rm = (const float*)d_in[3];
    float* out = (float*)d_out;

    float* ws    = (float*)d_ws;
    float* alpha = ws;                         // B*H*W floats
    float* pre   = ws + NPIX;                  // B*H*W floats
    unsigned short* w0b = (unsigned short*)(ws + 2 * NPIX);  // 128*64 bf16
    unsigned short* w1b = w0b + HID * 64;                    // 16*128 bf16

    prep<<<32, 256, 0, stream>>>(w0, w1, w0b, w1b);

    dim3 grid(WW / TS, HH / TS, BB);
    dim3 blk(TS, TS);
    pass1<<<grid, blk, 0, stream>>>(x, w0b, w1b, rm, out, alpha, pre);
    pass2<<<grid, blk, 0, stream>>>(alpha, pre, out);
}

// Round 4
// 189.949 us; speedup vs baseline: 2.2622x; 1.0409x over previous
//
#include <hip/hip_runtime.h>

#define BB 16
#define HH 256
#define WW 256
#define CC 16
#define HID 128
#define TS 16
#define NPIX ((size_t)BB * HH * WW)
#define KEXP 160   // 9 taps x 16 ch = 144, padded to 160 (tap 9 = zero weights)
#define XSTR 24    // xt pixel stride in bf16 (16 ch + 8 pad, 48 B)
#define HSTR 40    // H row stride in bf16 (32 + 8 pad)

typedef __attribute__((ext_vector_type(8))) short short8;
typedef __attribute__((ext_vector_type(4))) float floatx4;

__device__ inline unsigned int f2bf(float f) {
    unsigned int u = __float_as_uint(f);
    return (u + 0x7FFFu + ((u >> 16) & 1u)) >> 16;   // RNE (prep only)
}
// truncating bf16x2 pack: one v_perm_b32. mem order: lo then hi.
__device__ inline unsigned int packtr(float lo, float hi) {
    return __builtin_amdgcn_perm(__float_as_uint(hi), __float_as_uint(lo), 0x07060302u);
}

// ---------------------------------------------------------------------------
// prep: w0e[n][t*16+c] = sobel-folded first-layer weights (128 x 160 bf16,
// cols 144..159 zero). w1b[o][c_hid] = 16 x 128 bf16.
// ident(t)=(t==4); sx(dy,dx)=(dx-1)*(dy==1?2:1)/8; sy(dy,dx)=(dy-1)*(dx==1?2:1)/8
// ---------------------------------------------------------------------------
__global__ void prep(const float* __restrict__ w0, const float* __restrict__ w1,
                     unsigned short* __restrict__ w0e, unsigned short* __restrict__ w1b) {
    int i = blockIdx.x * blockDim.x + threadIdx.x;
    if (i < HID * KEXP) {
        int n = i / KEXP, k = i % KEXP;
        int t = k >> 4, c = k & 15;
        float v = 0.f;
        if (t < 9) {
            int dy = t / 3, dx = t % 3;
            float id = (t == 4) ? 1.f : 0.f;
            float sx = (float)(dx - 1) * ((dy == 1) ? 2.f : 1.f) * 0.125f;
            float sy = (float)(dy - 1) * ((dx == 1) ? 2.f : 1.f) * 0.125f;
            v = w0[n * 48 + 3 * c] * id + w0[n * 48 + 3 * c + 1] * sx
              + w0[n * 48 + 3 * c + 2] * sy;
        }
        w0e[i] = (unsigned short)f2bf(v);
    }
    if (i < CC * HID) w1b[i] = (unsigned short)f2bf(w1[i]);
}

// ---------------------------------------------------------------------------
// pass1: stage x tile (bf16) -> MFMA does conv+MLP fused (K=160 gathered taps)
// GEMM1: H^T[n][p] = sum_k W0e[n][k] Xg[p][k], k=(tap,ch); B-frags gathered
//        from xt at per-(ks,quad) tap offsets.
// GEMM2: DX^T[o][p] = sum_h W1[o][h] H[p][h], in 4 hid-quarters of 32.
// C/D layout: col=lane&15, row=quad*4+reg (m89/m91-verified)
// LDS: xt 15552 + at 1296 + Hb 10240 = 27088 B
// ---------------------------------------------------------------------------
__global__ __launch_bounds__(256)
void pass1(const float* __restrict__ x, const unsigned short* __restrict__ w0e,
           const unsigned short* __restrict__ w1b, const float* __restrict__ rand_mask,
           float* __restrict__ xn_out, float* __restrict__ alpha_out,
           float* __restrict__ pre_out)
{
    __shared__ unsigned short xt[18 * 18 * XSTR];          // bf16 halo tile
    __shared__ float at[18 * 18];                          // alpha (ch3) fp32 plane
    __shared__ unsigned short Hb[4][2][16 * HSTR];         // per-wave ping-pong H

    const int tx = threadIdx.x, ty = threadIdx.y;
    const int bx = blockIdx.x * TS, by = blockIdx.y * TS, b = blockIdx.z;
    const int tid = ty * TS + tx;
    const float* xb = x + (size_t)b * HH * WW * CC;

    // ---- stage halo tile: fp32 global -> bf16 LDS (+ alpha plane) ----
    for (int idx = tid; idx < 18 * 18 * 4; idx += 256) {
        int cq = idx & 3, p = idx >> 2;
        int lyy = p / 18, lxx = p % 18;
        int gy = by + lyy - 1, gx = bx + lxx - 1;
        float4 v = make_float4(0.f, 0.f, 0.f, 0.f);
        if (gy >= 0 && gy < HH && gx >= 0 && gx < WW)
            v = *(const float4*)(xb + (size_t)(gy * WW + gx) * CC + cq * 4);
        *(uint2*)(xt + p * XSTR + cq * 4) = make_uint2(packtr(v.x, v.y), packtr(v.z, v.w));
        if (cq == 0) at[p] = v.w;   // channel 3
    }
    __syncthreads();

    // ---- pre_life: 3x3 max of alpha > 0.1 ----
    {
        float m = -1.f;
        #pragma unroll
        for (int dy = 0; dy < 3; ++dy) {
            const float* r = at + (ty + dy) * 18 + tx;
            m = fmaxf(m, fmaxf(fmaxf(r[0], r[1]), r[2]));
        }
        const size_t pix0 = (size_t)b * HH * WW + (size_t)(by + ty) * WW + (bx + tx);
        pre_out[pix0] = (m > 0.1f) ? 1.f : 0.f;
    }

    // ---- MFMA phase: wave w owns pixels [64w, 64w+64), 4 nt-tiles of 16 ----
    const int w = tid >> 6, lane = tid & 63;
    const int quad = lane >> 4, lr = lane & 15;
    const int qh = quad >> 1, c0 = (quad & 1) * 8;

    // per-lane tap offsets (bf16 units) for ks=0..4: t = 2ks + qh (clamped to 8)
    // off(t) = ((t/3)*18 + t%3) * XSTR
    const int off0 = qh ? (1 * XSTR) : 0;
    const int off1 = qh ? (18 * XSTR + 0 * XSTR) : (2 * XSTR);
    const int off2 = qh ? (18 * XSTR + 2 * XSTR) : (18 * XSTR + 1 * XSTR);
    const int off3 = qh ? (36 * XSTR + 1 * XSTR) : (36 * XSTR + 0 * XSTR);
    const int off4 = 36 * XSTR + 2 * XSTR;   // t=8 both (qh=1 side has zero weights)

    floatx4 dacc[4] = {{0.f,0.f,0.f,0.f},{0.f,0.f,0.f,0.f},
                       {0.f,0.f,0.f,0.f},{0.f,0.f,0.f,0.f}};

    #pragma unroll 1
    for (int q = 0; q < 4; ++q) {
        // A-frags for this hid-quarter: 2 m-tiles x 5 k-steps (40 VGPRs)
        short8 A0[2][5];
        #pragma unroll
        for (int mt = 0; mt < 2; ++mt)
            #pragma unroll
            for (int ks = 0; ks < 5; ++ks)
                A0[mt][ks] = *(const short8*)(w0e + (q * 32 + mt * 16 + lr) * KEXP
                                              + ks * 32 + quad * 8);
        const short8 A1q = *(const short8*)(w1b + lr * HID + q * 32 + quad * 8);

        #pragma unroll
        for (int nt = 0; nt < 4; ++nt) {
            const int base = ((w * 4 + nt) * 18 + lr) * XSTR + c0;
            short8 Bf0 = *(const short8*)(xt + base + off0);
            short8 Bf1 = *(const short8*)(xt + base + off1);
            short8 Bf2 = *(const short8*)(xt + base + off2);
            short8 Bf3 = *(const short8*)(xt + base + off3);
            short8 Bf4 = *(const short8*)(xt + base + off4);

            unsigned short* Hw = &Hb[w][nt & 1][0];
            #pragma unroll
            for (int mt = 0; mt < 2; ++mt) {
                floatx4 acc = {0.f, 0.f, 0.f, 0.f};
                acc = __builtin_amdgcn_mfma_f32_16x16x32_bf16(A0[mt][0], Bf0, acc, 0, 0, 0);
                acc = __builtin_amdgcn_mfma_f32_16x16x32_bf16(A0[mt][1], Bf1, acc, 0, 0, 0);
                acc = __builtin_amdgcn_mfma_f32_16x16x32_bf16(A0[mt][2], Bf2, acc, 0, 0, 0);
                acc = __builtin_amdgcn_mfma_f32_16x16x32_bf16(A0[mt][3], Bf3, acc, 0, 0, 0);
                acc = __builtin_amdgcn_mfma_f32_16x16x32_bf16(A0[mt][4], Bf4, acc, 0, 0, 0);
                // lane holds H[pixel=lr][hid = q*32 + mt*16 + quad*4 + r]
                unsigned int lo = packtr(fmaxf(acc[0], 0.f), fmaxf(acc[1], 0.f));
                unsigned int hi = packtr(fmaxf(acc[2], 0.f), fmaxf(acc[3], 0.f));
                *(uint2*)(Hw + lr * HSTR + mt * 16 + quad * 4) = make_uint2(lo, hi);
            }
            // RAW: cross-lane H writes must land before B-read (also retires
            // the other buffer's reads from 2 iterations ago -> WAR safe)
            asm volatile("s_waitcnt lgkmcnt(0)" ::: "memory");
            short8 Bh = *(const short8*)(Hw + lr * HSTR + quad * 8);
            dacc[nt] = __builtin_amdgcn_mfma_f32_16x16x32_bf16(A1q, Bh, dacc[nt], 0, 0, 0);
        }
    }

    // ---- epilogue: lane holds dx[pixel = w*64+nt*16+lr][o = quad*4+r] ----
    #pragma unroll
    for (int nt = 0; nt < 4; ++nt) {
        const int gy = by + w * 4 + nt, gx = bx + lr;
        const size_t pix = (size_t)b * HH * WW + (size_t)gy * WW + gx;
        const float upd = (rand_mask[pix] <= 0.5f) ? 1.f : 0.f;
        const float4 xc = *(const float4*)(x + pix * CC + quad * 4);
        float4 xn;
        xn.x = xc.x + dacc[nt][0] * upd;
        xn.y = xc.y + dacc[nt][1] * upd;
        xn.z = xc.z + dacc[nt][2] * upd;
        xn.w = xc.w + dacc[nt][3] * upd;
        *(float4*)(xn_out + pix * CC + quad * 4) = xn;
        if (quad == 0) alpha_out[pix] = xn.w;   // channel 3
    }
}

// ---------------------------------------------------------------------------
// pass2: out already holds xn; zero only dead pixels (life==0).
// ---------------------------------------------------------------------------
#define TP (TS + 2)
__global__ __launch_bounds__(256)
void pass2(const float* __restrict__ alpha, const float* __restrict__ pre,
           float* __restrict__ out)
{
    __shared__ float at2[TP][TP];
    const int tx = threadIdx.x, ty = threadIdx.y;
    const int bx = blockIdx.x * TS, by = blockIdx.y * TS, b = blockIdx.z;
    const int tid = ty * TS + tx;
    const float* ab = alpha + (size_t)b * HH * WW;

    for (int idx = tid; idx < TP * TP; idx += 256) {
        int ly = idx / TP, lx = idx % TP;
        int gy = by + ly - 1, gx = bx + lx - 1;
        float v = 0.f;
        if (gy >= 0 && gy < HH && gx >= 0 && gx < WW) v = ab[gy * WW + gx];
        at2[ly][lx] = v;
    }
    __syncthreads();

    const int ly = ty + 1, lx = tx + 1;
    float m0 = fmaxf(fmaxf(at2[ly - 1][lx - 1], at2[ly - 1][lx]), at2[ly - 1][lx + 1]);
    float m1 = fmaxf(fmaxf(at2[ly    ][lx - 1], at2[ly    ][lx]), at2[ly    ][lx + 1]);
    float m2 = fmaxf(fmaxf(at2[ly + 1][lx - 1], at2[ly + 1][lx]), at2[ly + 1][lx + 1]);
    float m = fmaxf(fmaxf(m0, m1), m2);

    const size_t pix = (size_t)b * HH * WW + (size_t)(by + ty) * WW + (bx + tx);
    const bool dead = !(m > 0.1f && pre[pix] > 0.5f);

    if (dead) {
        float4 z = make_float4(0.f, 0.f, 0.f, 0.f);
        float4* o4 = (float4*)(out + pix * CC);
        #pragma unroll
        for (int i = 0; i < 4; ++i) o4[i] = z;
    }
}

extern "C" void kernel_launch(void* const* d_in, const int* in_sizes, int n_in,
                              void* d_out, int out_size, void* d_ws, size_t ws_size,
                              hipStream_t stream) {
    const float* x  = (const float*)d_in[0];
    const float* w0 = (const float*)d_in[1];
    const float* w1 = (const float*)d_in[2];
    const float* rm = (const float*)d_in[3];
    float* out = (float*)d_out;

    float* ws    = (float*)d_ws;
    float* alpha = ws;                         // B*H*W floats
    float* pre   = ws + NPIX;                  // B*H*W floats
    unsigned short* w0e = (unsigned short*)(ws + 2 * NPIX);  // 128*160 bf16
    unsigned short* w1b = w0e + HID * KEXP;                  // 16*128 bf16

    prep<<<(HID * KEXP + 255) / 256, 256, 0, stream>>>(w0, w1, w0e, w1b);

    dim3 grid(WW / TS, HH / TS, BB);
    dim3 blk(TS, TS);
    pass1<<<grid, blk, 0, stream>>>(x, w0e, w1b, rm, out, alpha, pre);
    pass2<<<grid, blk, 0, stream>>>(alpha, pre, out);
}